// Round 11
// baseline (51.404 us; speedup 1.0000x reference)
//
#include <hip/hip_runtime.h>

// Slab-ocean 1D explicit Euler, parallel-in-time via ring-down truncation.
//   z = U + iV,  z_{n+1} = a*z_n + b_n,  a = (1 - dt*K1) + i*(-dt*fc) const.
// Hour-level: z_{k+1} = A z_k + S_k,  A = a^60,  S_k = cA*w_k + cB*w_{k+1}.
// |A| <= ~0.67: z_k = sum_m E_m w_m over the last NW=32 samples (>=31
// transitions; truncation |A|^31*0.15 ~ 6e-7, 3 decades under the 4.88e-4
// fp32 noise floor every round has shown).
//   E_m: m==k -> cB;  m==0 -> A^{k-1} cA;  0<m<k -> A^{k-1-m} cC;  cC=cA+A*cB.
//
// r10 (50.6 us, best): XCD swizzle + NW=32 confirmed the L2-locality theory.
// THIS ROUND: single-variable A/B -- NT store -> PLAIN float4 store.
// r9's regression (56.4->67.8) conflated {plain stores, split 36KB staging,
// no swizzle}; the fills prove plain dwordx4 streams at 6.8-7.0 TB/s (35-40%
// above any NT rate we've measured). With r10's swizzle the per-XCD staged
// read set (~1 MB) is re-touched by every block in the XCD's contiguous
// k-range (stays LRU-warm) while write lines are dead-on-arrival and age out
// -- plain stores should not thrash the reads. Pre-committed read:
//   dur ~42-47 -> r9 was structural, plain wins;  >=55 -> NT is load-bearing,
//   revert permanently.
// Everything else bit-identical to r10:
//   - contiguous 84-chunk k-range per XCD: k = (bid&7)*84 + bid>>3
//   - combined 72 KB staging ([256 pts][36-float padded rows], b128-optimal)
//   - register weight table, z-exchange in dead LDS, r2-verified write loop.
// Single plain launch, grid = 672 blocks (block = chunk k), 256 threads.

#define NT    40320
#define BPTS  1024
#define NF    672
#define NSUB  60
#define CH    60                 // steps per chunk = 1 forcing hour
#define NCH   (NT / CH)          // 672
#define PPT   4                  // points per thread in write -> float4 stores
#define NW    32                 // window samples loaded (8 float4)
#define NV    (NW / 4)           // 8 float4 vectors per row
#define LSTR  36                 // LDS row stride in floats (bank-optimal pad)
#define TP    256                // points per staging tile
#define NTILE (BPTS / TP)        // 4 tiles
#define NXCD  8

typedef float vf4 __attribute__((ext_vector_type(4)));

__global__ __launch_bounds__(256, 2)
void slab_chunk(const float* __restrict__ pk,
                const float* __restrict__ TAx,
                const float* __restrict__ TAy,
                const float* __restrict__ fcp,
                const int* __restrict__ dtp,
                float* __restrict__ out) {
    // XCD-aware swizzle: contiguous k-range of 84 chunks per XCD.
    const int bid = blockIdx.x;
    const int k   = (bid & (NXCD - 1)) * (NCH / NXCD) + (bid >> 3);
    const int tid = threadIdx.x;

    // ---- model coefficients ----
    const float dtf = (float)dtp[0];
    const float K0  = expf(pk[0]);
    const float K1  = expf(pk[1]);
    const float ar  = 1.0f - dtf * K1;    // Re(a)
    const float ai  = -dtf * fcp[0];      // Im(a)
    const float bs  = dtf * K0;           // forcing scale

    // g1 = sum a^m, g2 = sum ((59-m)/60) a^m, A = a^60  (one 60-iter pass)
    float g1r = 0.f, g1i = 0.f, g2r = 0.f, g2i = 0.f;
    float pr = 1.f, pi = 0.f;
    for (int m = 0; m < NSUB; ++m) {
        g1r += pr; g1i += pi;
        float w = (float)(NSUB - 1 - m) * (1.0f / NSUB);
        g2r = fmaf(w, pr, g2r); g2i = fmaf(w, pi, g2i);
        float nr = pr * ar - pi * ai;
        float ni = pr * ai + pi * ar;
        pr = nr; pi = ni;
    }
    const float Ar  = pr,        Ai  = pi;          // A = a^CH
    const float cAr = g1r - g2r, cAi = g1i - g2i;   // coeff of w_k     in S_k
    const float cBr = g2r,       cBi = g2i;         // coeff of w_{k+1} in S_k
    const float cCr = cAr + (Ar * cBr - Ai * cBi);  // cC = cA + A*cB
    const float cCi = cAi + (Ar * cBi + Ai * cBr);

    // ---- window geometry: samples [ja, ja+NW), 4-aligned; ja<0 for small k
    // (negative slots get zero weight; their loads clamp to offset 0) ----
    int va = (k + 4) & ~3;                // aligned exclusive end, va-1 >= k
    if (va > NF) va = NF;
    const int ja = va - NW;               // may be negative

    // ---- register weight table (fully unrolled -> stays in VGPRs) ----
    float wgtR[NW], wgtI[NW];
    {
        float Wr = 1.f, Wi = 0.f;         // tracks A^{k-1-m}; =1 at m=k-1
#pragma unroll
        for (int i = NW - 1; i >= 0; --i) {
            const int m = ja + i;
            float er = 0.f, ei = 0.f;
            if (k > 0 && m >= 0 && m <= k) {
                if (m == k) { er = cBr; ei = cBi; }
                else {
                    const float br = (m == 0) ? cAr : cCr;
                    const float bi = (m == 0) ? cAi : cCi;
                    er = Wr * br - Wi * bi;
                    ei = Wr * bi + Wi * br;
                    const float t2 = Wr * Ar - Wi * Ai;
                    Wi = Wr * Ai + Wi * Ar; Wr = t2;
                }
            }
            wgtR[i] = er; wgtI[i] = ei;
        }
    }

    // ---- stage 1: tile-staged coalesced window -> per-point z ----
    __shared__ float ldsx[TP][LSTR];      // 36.9 KB (rows padded to 36 floats)
    __shared__ float ldsy[TP][LSTR];      // 36.9 KB
    float zr4[NTILE], zi4[NTILE];

#pragma unroll
    for (int tau = 0; tau < NTILE; ++tau) {
        // load tile tau: V -> (row=V/8, vec=V%8); lanes walk vf4s within rows
#pragma unroll
        for (int it = 0; it < NV; ++it) {
            const int V = tid + 256 * it;     // 0..2047 (256 rows x 8 vecs)
            const int r = V >> 3;
            const int v = V & 7;
            int off = ja + 4 * v; if (off < 0) off = 0;   // clamp (zero-weight)
            const size_t gbase = (size_t)(tau * TP + r) * NF + off;
            *(vf4*)&ldsx[r][4 * v] = *(const vf4*)(TAx + gbase);
            *(vf4*)&ldsy[r][4 * v] = *(const vf4*)(TAy + gbase);
        }
        __syncthreads();

        // consume: thread t owns point tau*TP + t (row t of the tile)
        float aR = 0.f, aI = 0.f;
#pragma unroll
        for (int v = 0; v < NV; ++v) {
            const vf4 fx = *(const vf4*)&ldsx[tid][4 * v];
            const vf4 fy = *(const vf4*)&ldsy[tid][4 * v];
#pragma unroll
            for (int e = 0; e < 4; ++e) {
                const int i = 4 * v + e;
                aR = fmaf(wgtR[i], fx[e], fmaf(-wgtI[i], fy[e], aR));
                aI = fmaf(wgtR[i], fy[e], fmaf( wgtI[i], fx[e], aI));
            }
        }
        zr4[tau] = bs * aR; zi4[tau] = bs * aI;
        __syncthreads();                  // before next tile overwrites LDS
    }

    // ---- z-exchange: interleaved ownership -> consecutive p0=4*tid ----
    float2* zbuf = (float2*)&ldsx[0][0];  // 8 KB in dead tile LDS
#pragma unroll
    for (int tau = 0; tau < NTILE; ++tau)
        zbuf[tau * TP + tid] = make_float2(zr4[tau], zi4[tau]);
    __syncthreads();

    const int p0 = tid * PPT;
    float zr[PPT], zi[PPT];
#pragma unroll
    for (int j = 0; j < PPT; ++j) {
        float2 z = zbuf[p0 + j];
        zr[j] = z.x; zi[j] = z.y;
    }

    // ---- stage 2: re-run chunk k exactly, stream U rows (r2-verified) ----
    const int f0 = k;
    const int f1 = (k + 1 < NF) ? k + 1 : NF - 1;

    float bx[PPT], by[PPT], dbx[PPT], dby[PPT];
#pragma unroll
    for (int j = 0; j < PPT; ++j) {
        const float* rx = TAx + (size_t)(p0 + j) * NF;
        const float* ry = TAy + (size_t)(p0 + j) * NF;
        const float x0 = rx[f0], x1 = rx[f1];
        const float y0 = ry[f0], y1 = ry[f1];
        bx[j]  = bs * x0;
        by[j]  = bs * y0;
        dbx[j] = bs * (x1 - x0) * (1.0f / NSUB);
        dby[j] = bs * (y1 - y0) * (1.0f / NSUB);
    }

    float* orow = out + (size_t)k * CH * BPTS + p0;

#pragma unroll 10
    for (int s = 0; s < CH; ++s) {
#pragma unroll
        for (int j = 0; j < PPT; ++j) {
            const float ur = fmaf(ar, zr[j], fmaf(-ai, zi[j], bx[j]));
            const float vi = fmaf(ar, zi[j], fmaf( ai, zr[j], by[j]));
            zr[j] = ur; zi[j] = vi;
            bx[j] += dbx[j]; by[j] += dby[j];
        }
        vf4 v; v.x = zr[0]; v.y = zr[1]; v.z = zr[2]; v.w = zr[3];
        *(vf4*)orow = v;                   // A/B: plain store (only change vs r10)
        orow += BPTS;
    }
}

extern "C" void kernel_launch(void* const* d_in, const int* in_sizes, int n_in,
                              void* d_out, int out_size, void* d_ws, size_t ws_size,
                              hipStream_t stream) {
    const float* pk  = (const float*)d_in[0];
    const float* TAx = (const float*)d_in[1];
    const float* TAy = (const float*)d_in[2];
    const float* fcp = (const float*)d_in[3];
    const int*   dtp = (const int*)d_in[5];   // dt = 60
    float* out = (float*)d_out;

    slab_chunk<<<NCH, 256, 0, stream>>>(pk, TAx, TAy, fcp, dtp, out);
}

// Round 12
// 49.007 us; speedup vs baseline: 1.0489x; 1.0489x over previous
//
#include <hip/hip_runtime.h>

// Slab-ocean 1D explicit Euler, parallel-in-time via ring-down truncation.
//   z = U + iV,  z_{n+1} = a*z_n + b_n,  a = (1 - dt*K1) + i*(-dt*fc) const.
// Hour-level: z_{k+1} = A z_k + S_k,  A = a^60,  S_k = cA*w_k + cB*w_{k+1}.
// |A| <= ~0.67: z_k = sum_m E_m w_m over the last NW=32 samples (>=31
// transitions; truncation ~6e-7, 3 decades under the 4.88e-4 fp32 noise
// floor every round has shown).
//
// r11 post-mortem: NT-vs-plain A/B was NULL (50.6 vs 51.4) -> store path is
// not a lever; remaining cost is stage-1 (lockstep staging ~13-15 us before
// any store issues). This round cuts stage-1 twice:
//   1) CG=2 EXACT CHUNK-CHAINING (r6-proven): stage-2's final z after 60
//      steps IS z(k+1); block owns chunks {2kp, 2kp+1}, ONE window sum.
//      Grid 672->336: chip staging work halves. 64 KB LDS -> 2 blocks/CU,
//      all 336 co-resident; write stays HBM-aggregate-bound.
//   2) global_load_lds staging (no VGPR round-trip, no ds_write instrs).
//      Linear LDS dest required -> both-sides XOR swizzle replaces the pad:
//      stage global vec uu = u^(r&7) into linear slot (r,u); read back at
//      (t, v^(t&7)). Bank spread identical to r10's 36-float pad layout.
//      Clamped negative offsets land only in zero-weight slots.
// Keep: XCD swizzle (contiguous 42 pairs = 84 chunks per XCD), NT stores,
// register weight table, z-exchange, r2-verified write body.
// Single plain launch, grid = 336 blocks, 256 threads.

#define NT    40320
#define BPTS  1024
#define NF    672
#define NSUB  60
#define CH    60                 // steps per chunk = 1 forcing hour
#define NCH   (NT / CH)          // 672
#define CG    2                  // chunks per block (exact chaining)
#define NPAIR (NCH / CG)         // 336 blocks
#define PPT   4                  // points per thread in write -> float4 stores
#define NW    32                 // window samples loaded (8 float4)
#define NV    (NW / 4)           // 8 float4 vectors per row
#define TP    256                // points per staging tile
#define NTILE (BPTS / TP)        // 4 tiles
#define NXCD  8

typedef float vf4 __attribute__((ext_vector_type(4)));

__device__ __forceinline__ void gload_lds16(const float* g, float* l) {
    __builtin_amdgcn_global_load_lds(
        (const __attribute__((address_space(1))) void*)g,
        (__attribute__((address_space(3))) void*)l, 16, 0, 0);
}

__global__ __launch_bounds__(256, 2)
void slab_chunk(const float* __restrict__ pk,
                const float* __restrict__ TAx,
                const float* __restrict__ TAy,
                const float* __restrict__ fcp,
                const int* __restrict__ dtp,
                float* __restrict__ out) {
    // XCD-aware swizzle: contiguous 42 chunk-pairs (84 chunks) per XCD.
    const int bid = blockIdx.x;
    const int kp  = (bid & (NXCD - 1)) * (NPAIR / NXCD) + (bid >> 3);
    const int k0  = kp * CG;              // first chunk of this block
    const int tid = threadIdx.x;

    // ---- model coefficients ----
    const float dtf = (float)dtp[0];
    const float K0  = expf(pk[0]);
    const float K1  = expf(pk[1]);
    const float ar  = 1.0f - dtf * K1;    // Re(a)
    const float ai  = -dtf * fcp[0];      // Im(a)
    const float bs  = dtf * K0;           // forcing scale

    // g1 = sum a^m, g2 = sum ((59-m)/60) a^m, A = a^60  (one 60-iter pass)
    float g1r = 0.f, g1i = 0.f, g2r = 0.f, g2i = 0.f;
    float pr = 1.f, pi = 0.f;
    for (int m = 0; m < NSUB; ++m) {
        g1r += pr; g1i += pi;
        float w = (float)(NSUB - 1 - m) * (1.0f / NSUB);
        g2r = fmaf(w, pr, g2r); g2i = fmaf(w, pi, g2i);
        float nr = pr * ar - pi * ai;
        float ni = pr * ai + pi * ar;
        pr = nr; pi = ni;
    }
    const float Ar  = pr,        Ai  = pi;          // A = a^CH
    const float cAr = g1r - g2r, cAi = g1i - g2i;   // coeff of w_k     in S_k
    const float cBr = g2r,       cBi = g2i;         // coeff of w_{k+1} in S_k
    const float cCr = cAr + (Ar * cBr - Ai * cBi);  // cC = cA + A*cB
    const float cCi = cAi + (Ar * cBi + Ai * cBr);

    // ---- window geometry for chunk k0: samples [ja, ja+NW), 4-aligned ----
    int va = (k0 + 4) & ~3;               // aligned exclusive end, va-1 >= k0
    if (va > NF) va = NF;
    const int ja = va - NW;               // may be negative (zero-weight slots)

    // ---- register weight table (fully unrolled -> stays in VGPRs) ----
    float wgtR[NW], wgtI[NW];
    {
        float Wr = 1.f, Wi = 0.f;         // tracks A^{k0-1-m}; =1 at m=k0-1
#pragma unroll
        for (int i = NW - 1; i >= 0; --i) {
            const int m = ja + i;
            float er = 0.f, ei = 0.f;
            if (k0 > 0 && m >= 0 && m <= k0) {
                if (m == k0) { er = cBr; ei = cBi; }
                else {
                    const float br = (m == 0) ? cAr : cCr;
                    const float bi = (m == 0) ? cAi : cCi;
                    er = Wr * br - Wi * bi;
                    ei = Wr * bi + Wi * br;
                    const float t2 = Wr * Ar - Wi * Ai;
                    Wi = Wr * Ai + Wi * Ar; Wr = t2;
                }
            }
            wgtR[i] = er; wgtI[i] = ei;
        }
    }

    // ---- stage 1: global_load_lds-staged window -> per-point z ----
    // Linear LDS [256 pts][32 smp]; slot (r,u) holds global vec u^(r&7).
    __shared__ float ldsx[TP][NW];        // 32 KB
    __shared__ float ldsy[TP][NW];        // 32 KB
    float zr4[NTILE], zi4[NTILE];

#pragma unroll
    for (int tau = 0; tau < NTILE; ++tau) {
        // stage tile tau: V -> slot(r=V>>3, u=V&7); dest = base + lane*16
#pragma unroll
        for (int it = 0; it < NV; ++it) {
            const int V  = tid + 256 * it;    // 0..2047
            const int r  = V >> 3;
            const int u  = V & 7;
            const int uu = u ^ (r & 7);       // pre-swizzled source vec
            int off = ja + 4 * uu; if (off < 0) off = 0;  // clamp (zero-weight)
            const size_t gb = (size_t)(tau * TP + r) * NF + off;
            gload_lds16(TAx + gb, &ldsx[0][0] + (size_t)V * 4);
            gload_lds16(TAy + gb, &ldsy[0][0] + (size_t)V * 4);
        }
        __syncthreads();                  // drains vmcnt before barrier

        // consume: thread t owns point tau*TP + t; read swizzled slots
        float aR = 0.f, aI = 0.f;
#pragma unroll
        for (int v = 0; v < NV; ++v) {
            const int sv = v ^ (tid & 7);     // swizzled slot for global vec v
            const vf4 fx = *(const vf4*)&ldsx[tid][4 * sv];
            const vf4 fy = *(const vf4*)&ldsy[tid][4 * sv];
#pragma unroll
            for (int e = 0; e < 4; ++e) {
                const int i = 4 * v + e;
                aR = fmaf(wgtR[i], fx[e], fmaf(-wgtI[i], fy[e], aR));
                aI = fmaf(wgtR[i], fy[e], fmaf( wgtI[i], fx[e], aI));
            }
        }
        zr4[tau] = bs * aR; zi4[tau] = bs * aI;
        __syncthreads();                  // before next tile overwrites LDS
    }

    // ---- z-exchange: interleaved ownership -> consecutive p0=4*tid ----
    float2* zbuf = (float2*)&ldsx[0][0];  // 8 KB in dead tile LDS
#pragma unroll
    for (int tau = 0; tau < NTILE; ++tau)
        zbuf[tau * TP + tid] = make_float2(zr4[tau], zi4[tau]);
    __syncthreads();

    const int p0 = tid * PPT;
    float zr[PPT], zi[PPT];
#pragma unroll
    for (int j = 0; j < PPT; ++j) {
        float2 z = zbuf[p0 + j];
        zr[j] = z.x; zi[j] = z.y;
    }

    // ---- stage 2: evolve exactly through CG chunks, stream U rows ----
    float x0[PPT], y0[PPT];
#pragma unroll
    for (int j = 0; j < PPT; ++j) {
        x0[j] = TAx[(size_t)(p0 + j) * NF + k0];
        y0[j] = TAy[(size_t)(p0 + j) * NF + k0];
    }

    float* orow = out + (size_t)k0 * CH * BPTS + p0;

    for (int c = 0; c < CG; ++c) {
        const int kk = k0 + c;
        const int f1 = (kk + 1 < NF) ? kk + 1 : NF - 1;

        float x1[PPT], y1[PPT], bx[PPT], by[PPT], dbx[PPT], dby[PPT];
#pragma unroll
        for (int j = 0; j < PPT; ++j) {
            x1[j] = TAx[(size_t)(p0 + j) * NF + f1];
            y1[j] = TAy[(size_t)(p0 + j) * NF + f1];
            bx[j]  = bs * x0[j];
            by[j]  = bs * y0[j];
            dbx[j] = bs * (x1[j] - x0[j]) * (1.0f / NSUB);
            dby[j] = bs * (y1[j] - y0[j]) * (1.0f / NSUB);
        }

#pragma unroll 10
        for (int s = 0; s < CH; ++s) {
#pragma unroll
            for (int j = 0; j < PPT; ++j) {
                const float ur = fmaf(ar, zr[j], fmaf(-ai, zi[j], bx[j]));
                const float vi = fmaf(ar, zi[j], fmaf( ai, zr[j], by[j]));
                zr[j] = ur; zi[j] = vi;
                bx[j] += dbx[j]; by[j] += dby[j];
            }
            vf4 v; v.x = zr[0]; v.y = zr[1]; v.z = zr[2]; v.w = zr[3];
            __builtin_nontemporal_store(v, (vf4*)orow);
            orow += BPTS;
        }

#pragma unroll
        for (int j = 0; j < PPT; ++j) { x0[j] = x1[j]; y0[j] = y1[j]; }
    }
}

extern "C" void kernel_launch(void* const* d_in, const int* in_sizes, int n_in,
                              void* d_out, int out_size, void* d_ws, size_t ws_size,
                              hipStream_t stream) {
    const float* pk  = (const float*)d_in[0];
    const float* TAx = (const float*)d_in[1];
    const float* TAy = (const float*)d_in[2];
    const float* fcp = (const float*)d_in[3];
    const int*   dtp = (const int*)d_in[5];   // dt = 60
    float* out = (float*)d_out;

    slab_chunk<<<NPAIR, 256, 0, stream>>>(pk, TAx, TAy, fcp, dtp, out);
}